// Round 5
// baseline (555.492 us; speedup 1.0000x reference)
//
#include <hip/hip_runtime.h>
#include <stdint.h>

#define NSPACE 197
#define TFRAMES 8
#define NH 12
#define DIM 768
#define HD 64
#define BATCH 8
#define NQ 1576
#define NK 1576
#define M_REAL 12608   // BATCH*NQ
#define M_PAD 12672    // 99*128
#define VT_LD 1600     // NK padded so OOB key reads stay in-row

typedef __attribute__((ext_vector_type(8))) short s16x8;
typedef __attribute__((ext_vector_type(4))) short s16x4;
typedef __attribute__((ext_vector_type(4))) float f32x4;

__device__ inline uint16_t f2bf(float f) {
    union { float f; uint32_t i; } c; c.f = f;
    uint32_t r = c.i + 0x7FFF + ((c.i >> 16) & 1);
    return (uint16_t)(r >> 16);
}
// pack two floats -> two bf16 in one u32 (round-half-up; ties negligible for P)
__device__ inline uint32_t pack2bf(float lo, float hi) {
    union { float f; uint32_t i; } a, b; a.f = lo; b.f = hi;
    return ((a.i + 0x8000u) >> 16) | ((b.i + 0x8000u) & 0xFFFF0000u);
}

// ---------------- fp32 -> bf16 converters ----------------

__global__ void conv_f2b(const float* __restrict__ src, uint16_t* __restrict__ dst, int n8) {
    int chunk = blockIdx.x * 256 + threadIdx.x;
    if (chunk >= n8) return;
    size_t off = (size_t)chunk * 8;
    float4 a = *(const float4*)(src + off);
    float4 b = *(const float4*)(src + off + 4);
    s16x8 o;
    o[0] = (short)f2bf(a.x); o[1] = (short)f2bf(a.y);
    o[2] = (short)f2bf(a.z); o[3] = (short)f2bf(a.w);
    o[4] = (short)f2bf(b.x); o[5] = (short)f2bf(b.y);
    o[6] = (short)f2bf(b.z); o[7] = (short)f2bf(b.w);
    *(s16x8*)(dst + off) = o;
}

__global__ void fill_x(const float* __restrict__ t_x, uint16_t* __restrict__ x_pad) {
    int chunk = blockIdx.x * 256 + threadIdx.x;             // 8 elems per chunk
    const int total = M_PAD * (DIM / 8);
    if (chunk >= total) return;
    size_t off = (size_t)chunk * 8;
    s16x8 o;
    if (off < (size_t)M_REAL * DIM) {
        float4 a = *(const float4*)(t_x + off);
        float4 b = *(const float4*)(t_x + off + 4);
        o[0] = (short)f2bf(a.x); o[1] = (short)f2bf(a.y);
        o[2] = (short)f2bf(a.z); o[3] = (short)f2bf(a.w);
        o[4] = (short)f2bf(b.x); o[5] = (short)f2bf(b.y);
        o[6] = (short)f2bf(b.z); o[7] = (short)f2bf(b.w);
    } else {
        for (int j = 0; j < 8; j++) o[j] = 0;
    }
    *(s16x8*)(x_pad + off) = o;
}

__global__ void fill_s(const float* __restrict__ s_x, const float* __restrict__ pos,
                       uint16_t* __restrict__ s_pad) {
    int chunk = blockIdx.x * 256 + threadIdx.x;
    const int total = M_PAD * (DIM / 8);
    if (chunk >= total) return;
    int i = chunk / (DIM / 8);
    int cc = chunk - i * (DIM / 8);
    int d0 = cc * 8;
    uint16_t* dst = s_pad + (size_t)i * DIM + d0;
    if (i >= M_REAL) {
        s16x8 z; for (int j = 0; j < 8; j++) z[j] = 0;
        *(s16x8*)dst = z;
        return;
    }
    int b = i / NK, rr = i - b * NK;
    int t_i = rr / NSPACE, n_i = rr - t_i * NSPACE;
    const float* src = s_x + ((size_t)(n_i * (BATCH * TFRAMES) + b * TFRAMES + t_i)) * DIM + d0;
    const float* ps = pos + (size_t)rr * DIM + d0;
    float4 a0 = *(const float4*)src;
    float4 a1 = *(const float4*)(src + 4);
    float4 p0 = *(const float4*)ps;
    float4 p1 = *(const float4*)(ps + 4);
    s16x8 o;
    o[0] = (short)f2bf(a0.x + p0.x); o[1] = (short)f2bf(a0.y + p0.y);
    o[2] = (short)f2bf(a0.z + p0.z); o[3] = (short)f2bf(a0.w + p0.w);
    o[4] = (short)f2bf(a1.x + p1.x); o[5] = (short)f2bf(a1.y + p1.y);
    o[6] = (short)f2bf(a1.z + p1.z); o[7] = (short)f2bf(a1.w + p1.w);
    *(s16x8*)dst = o;
}

// ---------------- GEMM: C[M,N] = A[M,K=768] @ W[N,K=768]^T + bias ----------------
// MODE 0: Q    -> out0 = q_buf (B,H,NQ,64) bf16, scaled by 0.125*log2(e) (exp2 softmax)
// MODE 1: KV   -> out0 = k_buf (B,H,NK,64) bf16; out1 = v_buf (B,H,NK,64) bf16 row-major
// MODE 2: proj -> outf = row-major (M_REAL, 768) fp32 output
template <int MODE>
__global__ __launch_bounds__(256)
void gemm_bt(const uint16_t* __restrict__ A, const uint16_t* __restrict__ W,
             const float* __restrict__ bias,
             uint16_t* __restrict__ out0, uint16_t* __restrict__ out1,
             float* __restrict__ outf) {
    __shared__ uint16_t As[128 * 40];
    __shared__ uint16_t Bs[128 * 40];
    const int t = threadIdx.x;
    const int lane = t & 63, w = t >> 6;
    const int r16 = lane & 15, quad = lane >> 4;
    const int wm = w >> 1, wn = w & 1;
    const int m0 = blockIdx.y * 128;
    const int n0 = blockIdx.x * 128;

    f32x4 acc[4][4];
    for (int a = 0; a < 4; a++)
        for (int bb = 0; bb < 4; bb++)
            for (int r = 0; r < 4; r++) acc[a][bb][r] = 0.f;

    for (int kk = 0; kk < DIM; kk += 32) {
        for (int i2 = 0; i2 < 2; i2++) {
            int c = t + i2 * 256;            // 0..511 chunks of 8 elems
            int row = c >> 2, kc = (c & 3) * 8;
            *(s16x8*)&As[row * 40 + kc] = *(const s16x8*)&A[(size_t)(m0 + row) * DIM + kk + kc];
            *(s16x8*)&Bs[row * 40 + kc] = *(const s16x8*)&W[(size_t)(n0 + row) * DIM + kk + kc];
        }
        __syncthreads();
        s16x8 af[4], bfr[4];
        for (int mt = 0; mt < 4; mt++)
            af[mt] = *(const s16x8*)&As[(wm * 64 + mt * 16 + r16) * 40 + quad * 8];
        for (int nt = 0; nt < 4; nt++)
            bfr[nt] = *(const s16x8*)&Bs[(wn * 64 + nt * 16 + r16) * 40 + quad * 8];
        for (int mt = 0; mt < 4; mt++)
            for (int nt = 0; nt < 4; nt++)
                acc[mt][nt] = __builtin_amdgcn_mfma_f32_16x16x32_bf16(af[mt], bfr[nt], acc[mt][nt], 0, 0, 0);
        __syncthreads();
    }

    for (int mt = 0; mt < 4; mt++)
        for (int nt = 0; nt < 4; nt++) {
            int col = n0 + wn * 64 + nt * 16 + r16;
            float bz = bias[col];
            int rowb = m0 + wm * 64 + mt * 16 + quad * 4;
            for (int r = 0; r < 4; r++) {
                int i = rowb + r;
                if (i >= M_REAL) continue;
                float v = acc[mt][nt][r] + bz;
                if (MODE == 0) {
                    int b = i / NQ, nq = i - b * NQ;
                    int h = col >> 6, d = col & 63;
                    // 0.125 * log2(e): softmax done in exp2 domain in flash_attn
                    out0[(size_t)(((b * NH + h) * NQ) + nq) * HD + d] = f2bf(v * 0.18033688011112042f);
                } else if (MODE == 1) {
                    int b = i / NK, nk = i - b * NK;
                    if (col < DIM) {
                        int h = col >> 6, d = col & 63;
                        out0[(size_t)(((b * NH + h) * NK) + nk) * HD + d] = f2bf(v);
                    } else {
                        int c2 = col - DIM;
                        int h = c2 >> 6, d = c2 & 63;
                        out1[(size_t)(((b * NH + h) * NK) + nk) * HD + d] = f2bf(v);  // row-major
                    }
                } else {
                    outf[(size_t)i * DIM + col] = v;
                }
            }
        }
}

// ---------------- V transpose: (b,h,nk,64) -> (b,h,64,VT_LD) ----------------
__global__ __launch_bounds__(256)
void transpose_v(const uint16_t* __restrict__ v, uint16_t* __restrict__ vt) {
    __shared__ uint16_t T[64 * 72];
    int tile = blockIdx.x, bh = blockIdx.y;
    int nk0 = tile * 64;
    const uint16_t* V = v + (size_t)bh * NK * HD;
    uint16_t* VT = vt + (size_t)bh * HD * VT_LD;
    int tid = threadIdx.x;
    int rr = tid >> 3;          // 0..31
    int c8 = (tid & 7) * 8;     // 0..56
    for (int p = 0; p < 2; p++) {
        int lr = p * 32 + rr;
        int nk = nk0 + lr;
        s16x8 val;
        if (nk < NK) val = *(const s16x8*)(V + (size_t)nk * HD + c8);
        else for (int j = 0; j < 8; j++) val[j] = 0;
        for (int j = 0; j < 8; j++)
            T[(c8 + j) * 72 + lr] = (uint16_t)val[j];
    }
    __syncthreads();
    for (int p = 0; p < 2; p++) {
        int d = p * 32 + rr;
        s16x8 o = *(const s16x8*)&T[d * 72 + c8];
        *(s16x8*)(VT + (size_t)d * VT_LD + nk0 + c8) = o;
    }
}

// ---------------- flash attention v3: LDS-free, register-resident P ----------------
// S^T = mfma(A=K, B=Q) with key-permuted K rows so each lane's 8 p-values land
// exactly in PV's B-fragment order B[q=r16][k=quad*8+j]. Two QK^T mfma pairs:
//   tile A covers keys quad*8 + r   (K rows keymapA(m)=(m>>2)*8+(m&3))
//   tile B covers keys quad*8 + 4+r (K rows keymapA+4)
// PV: O^T = mfma(A=V^T, B=P): lane ends with O[q=r16][d=dt*16+quad*4+r].
// No LDS, no barriers, lsum is a per-lane scalar (2 shuffles at the end).
__global__ __launch_bounds__(64, 4)
void flash_attn(const uint16_t* __restrict__ q_buf, const uint16_t* __restrict__ k_buf,
                const uint16_t* __restrict__ vt_buf, uint16_t* __restrict__ ao) {
    int qt = blockIdx.x, h = blockIdx.y, b = blockIdx.z;
    int lane = threadIdx.x;
    int r16 = lane & 15, quad = lane >> 4;
    size_t bh = (size_t)(b * NH + h);
    const uint16_t* Q = q_buf + bh * NQ * HD;
    const uint16_t* K = k_buf + bh * NK * HD;
    const uint16_t* VT = vt_buf + bh * HD * VT_LD;
    int q0 = qt * 32;

    s16x8 qf[2][2];
    for (int m = 0; m < 2; m++) {
        int qrow = q0 + m * 16 + r16;
        if (qrow < NQ) {
            qf[m][0] = *(const s16x8*)(Q + (size_t)qrow * HD + quad * 8);
            qf[m][1] = *(const s16x8*)(Q + (size_t)qrow * HD + 32 + quad * 8);
        } else {
            for (int j = 0; j < 8; j++) { qf[m][0][j] = 0; qf[m][1][j] = 0; }
        }
    }

    f32x4 oT[2][4];
    f32x4 lsum4[2];
    for (int m = 0; m < 2; m++) {
        for (int dt = 0; dt < 4; dt++)
            for (int r = 0; r < 4; r++) oT[m][dt][r] = 0.f;
        for (int r = 0; r < 4; r++) lsum4[m][r] = 0.f;
    }

    const int rowA = ((r16 & 12) << 1) + (r16 & 3);   // keymapA(r16)

    for (int kb = 0; kb < NK; kb += 32) {
        // K fragments (rows kb+rowA and kb+rowA+4; last iter reads <=row 1599,
        // finite data inside the k_buf/vt_buf carves, masked below)
        const uint16_t* kp = K + (size_t)(kb + rowA) * HD + quad * 8;
        s16x8 kfA0 = *(const s16x8*)kp;
        s16x8 kfA1 = *(const s16x8*)(kp + 32);
        s16x8 kfB0 = *(const s16x8*)(kp + 4 * HD);
        s16x8 kfB1 = *(const s16x8*)(kp + 4 * HD + 32);

        s16x8 pf[2];
        if (kb + 32 <= NK) {
            #pragma unroll
            for (int m = 0; m < 2; m++) {
                f32x4 sA, sB;
                for (int r = 0; r < 4; r++) { sA[r] = 0.f; sB[r] = 0.f; }
                sA = __builtin_amdgcn_mfma_f32_16x16x32_bf16(kfA0, qf[m][0], sA, 0, 0, 0);
                sA = __builtin_amdgcn_mfma_f32_16x16x32_bf16(kfA1, qf[m][1], sA, 0, 0, 0);
                sB = __builtin_amdgcn_mfma_f32_16x16x32_bf16(kfB0, qf[m][0], sB, 0, 0, 0);
                sB = __builtin_amdgcn_mfma_f32_16x16x32_bf16(kfB1, qf[m][1], sB, 0, 0, 0);
                f32x4 pA, pB;
                #pragma unroll
                for (int r = 0; r < 4; r++) { pA[r] = exp2f(sA[r]); pB[r] = exp2f(sB[r]); }
                lsum4[m] += pA;
                lsum4[m] += pB;
                union { s16x8 v; uint32_t u[4]; } pk;
                pk.u[0] = pack2bf(pA[0], pA[1]);
                pk.u[1] = pack2bf(pA[2], pA[3]);
                pk.u[2] = pack2bf(pB[0], pB[1]);
                pk.u[3] = pack2bf(pB[2], pB[3]);
                pf[m] = pk.v;
            }
        } else {  // tail: mask keys >= NK
            #pragma unroll
            for (int m = 0; m < 2; m++) {
                f32x4 sA, sB;
                for (int r = 0; r < 4; r++) { sA[r] = 0.f; sB[r] = 0.f; }
                sA = __builtin_amdgcn_mfma_f32_16x16x32_bf16(kfA0, qf[m][0], sA, 0, 0, 0);
                sA = __builtin_amdgcn_mfma_f32_16x16x32_bf16(kfA1, qf[m][1], sA, 0, 0, 0);
                sB = __builtin_amdgcn_mfma_f32_16x16x32_bf16(kfB0, qf[m][0], sB, 0, 0, 0);
                sB = __builtin_amdgcn_mfma_f32_16x16x32_bf16(kfB1, qf[m][1], sB, 0, 0, 0);
                f32x4 pA, pB;
                #pragma unroll
                for (int r = 0; r < 4; r++) {
                    pA[r] = (kb + quad * 8 + r < NK)     ? exp2f(sA[r]) : 0.f;
                    pB[r] = (kb + quad * 8 + 4 + r < NK) ? exp2f(sB[r]) : 0.f;
                }
                lsum4[m] += pA;
                lsum4[m] += pB;
                union { s16x8 v; uint32_t u[4]; } pk;
                pk.u[0] = pack2bf(pA[0], pA[1]);
                pk.u[1] = pack2bf(pA[2], pA[3]);
                pk.u[2] = pack2bf(pB[0], pB[1]);
                pk.u[3] = pack2bf(pB[2], pB[3]);
                pf[m] = pk.v;
            }
        }
        #pragma unroll
        for (int dt = 0; dt < 4; dt++) {
            s16x8 vf = *(const s16x8*)(VT + (size_t)(dt * 16 + r16) * VT_LD + kb + quad * 8);
            oT[0][dt] = __builtin_amdgcn_mfma_f32_16x16x32_bf16(vf, pf[0], oT[0][dt], 0, 0, 0);
            oT[1][dt] = __builtin_amdgcn_mfma_f32_16x16x32_bf16(vf, pf[1], oT[1][dt], 0, 0, 0);
        }
    }

    #pragma unroll
    for (int m = 0; m < 2; m++) {
        float rs = lsum4[m][0] + lsum4[m][1] + lsum4[m][2] + lsum4[m][3];
        rs += __shfl_xor(rs, 16);
        rs += __shfl_xor(rs, 32);
        int q = q0 + m * 16 + r16;
        if (q >= NQ) continue;
        float inv = 1.0f / rs;
        size_t rowoff = (size_t)(b * NQ + q) * DIM + h * HD;
        #pragma unroll
        for (int dt = 0; dt < 4; dt++) {
            s16x4 o4;
            o4[0] = (short)f2bf(oT[m][dt][0] * inv);
            o4[1] = (short)f2bf(oT[m][dt][1] * inv);
            o4[2] = (short)f2bf(oT[m][dt][2] * inv);
            o4[3] = (short)f2bf(oT[m][dt][3] * inv);
            *(s16x4*)(ao + rowoff + dt * 16 + quad * 4) = o4;
        }
    }
}

// ---------------- launch ----------------
extern "C" void kernel_launch(void* const* d_in, const int* in_sizes, int n_in,
                              void* d_out, int out_size, void* d_ws, size_t ws_size,
                              hipStream_t stream) {
    const float* s_x    = (const float*)d_in[0];
    const float* t_x    = (const float*)d_in[1];
    const float* pos    = (const float*)d_in[2];
    const float* q_w    = (const float*)d_in[3];
    const float* q_b    = (const float*)d_in[4];
    const float* kv_w   = (const float*)d_in[5];
    const float* kv_b   = (const float*)d_in[6];
    const float* proj_w = (const float*)d_in[7];
    const float* proj_b = (const float*)d_in[8];
    float* out = (float*)d_out;

    char* ws = (char*)d_ws;
    size_t off = 0;
    auto carve = [&](size_t bytes) {
        void* p = ws + off;
        off += (bytes + 255) & ~(size_t)255;
        return p;
    };
    uint16_t* x_pad  = (uint16_t*)carve((size_t)M_PAD * DIM * 2);
    uint16_t* s_pad  = (uint16_t*)carve((size_t)M_PAD * DIM * 2);
    uint16_t* q_buf  = (uint16_t*)carve((size_t)BATCH * NH * NQ * HD * 2);
    uint16_t* k_buf  = (uint16_t*)carve((size_t)BATCH * NH * NK * HD * 2);
    uint16_t* vt_buf = (uint16_t*)carve((size_t)BATCH * NH * HD * VT_LD * 2);
    uint16_t* wbuf   = (uint16_t*)carve((size_t)2 * DIM * DIM * 2);
    if (off > ws_size) return;
    // lifetimes: x_pad (t_x copy) dead after Q GEMM -> reused as v_buf during
    // KV GEMM + transpose -> reused as ao from flash on (v_buf dead by then).
    uint16_t* v_buf = x_pad;
    uint16_t* ao    = x_pad;

    const int fill_blocks = (M_PAD * (DIM / 8) + 255) / 256;
    const int wq8 = DIM * DIM / 8, wkv8 = 2 * DIM * DIM / 8;

    fill_x<<<fill_blocks, 256, 0, stream>>>(t_x, x_pad);
    fill_s<<<fill_blocks, 256, 0, stream>>>(s_x, pos, s_pad);

    conv_f2b<<<(wq8 + 255) / 256, 256, 0, stream>>>(q_w, wbuf, wq8);
    gemm_bt<0><<<dim3(DIM / 128, M_PAD / 128), 256, 0, stream>>>(x_pad, wbuf, q_b, q_buf, nullptr, nullptr);

    conv_f2b<<<(wkv8 + 255) / 256, 256, 0, stream>>>(kv_w, wbuf, wkv8);
    gemm_bt<1><<<dim3(2 * DIM / 128, M_PAD / 128), 256, 0, stream>>>(s_pad, wbuf, kv_b, k_buf, v_buf, nullptr);
    transpose_v<<<dim3(VT_LD / 64, BATCH * NH), 256, 0, stream>>>(v_buf, vt_buf);

    flash_attn<<<dim3((NQ + 31) / 32, NH, BATCH), 64, 0, stream>>>(q_buf, k_buf, vt_buf, ao);

    conv_f2b<<<(wq8 + 255) / 256, 256, 0, stream>>>(proj_w, wbuf, wq8);
    gemm_bt<2><<<dim3(DIM / 128, M_PAD / 128), 256, 0, stream>>>(ao, wbuf, proj_b, nullptr, nullptr, out);
}

// Round 6
// 436.113 us; speedup vs baseline: 1.2737x; 1.2737x over previous
//
#include <hip/hip_runtime.h>
#include <stdint.h>

#define NSPACE 197
#define TFRAMES 8
#define NH 12
#define DIM 768
#define HD 64
#define BATCH 8
#define NQ 1576
#define NK 1576
#define M_REAL 12608   // BATCH*NQ
#define M_PAD 12672    // 99*128
#define VT_LD 1600     // NK padded so OOB key reads stay in-row

typedef __attribute__((ext_vector_type(8))) short s16x8;
typedef __attribute__((ext_vector_type(4))) short s16x4;
typedef __attribute__((ext_vector_type(4))) float f32x4;

__device__ inline uint16_t f2bf(float f) {
    union { float f; uint32_t i; } c; c.f = f;
    uint32_t r = c.i + 0x7FFF + ((c.i >> 16) & 1);
    return (uint16_t)(r >> 16);
}
__device__ inline uint32_t pack2bf(float lo, float hi) {
    union { float f; uint32_t i; } a, b; a.f = lo; b.f = hi;
    return ((a.i + 0x8000u) >> 16) | ((b.i + 0x8000u) & 0xFFFF0000u);
}

// ---------------- fp32 -> bf16 converters ----------------

__global__ void conv_f2b(const float* __restrict__ src, uint16_t* __restrict__ dst, int n8) {
    int chunk = blockIdx.x * 256 + threadIdx.x;
    if (chunk >= n8) return;
    size_t off = (size_t)chunk * 8;
    float4 a = *(const float4*)(src + off);
    float4 b = *(const float4*)(src + off + 4);
    s16x8 o;
    o[0] = (short)f2bf(a.x); o[1] = (short)f2bf(a.y);
    o[2] = (short)f2bf(a.z); o[3] = (short)f2bf(a.w);
    o[4] = (short)f2bf(b.x); o[5] = (short)f2bf(b.y);
    o[6] = (short)f2bf(b.z); o[7] = (short)f2bf(b.w);
    *(s16x8*)(dst + off) = o;
}

__global__ void fill_x(const float* __restrict__ t_x, uint16_t* __restrict__ x_pad) {
    int chunk = blockIdx.x * 256 + threadIdx.x;             // 8 elems per chunk
    const int total = M_PAD * (DIM / 8);
    if (chunk >= total) return;
    size_t off = (size_t)chunk * 8;
    s16x8 o;
    if (off < (size_t)M_REAL * DIM) {
        float4 a = *(const float4*)(t_x + off);
        float4 b = *(const float4*)(t_x + off + 4);
        o[0] = (short)f2bf(a.x); o[1] = (short)f2bf(a.y);
        o[2] = (short)f2bf(a.z); o[3] = (short)f2bf(a.w);
        o[4] = (short)f2bf(b.x); o[5] = (short)f2bf(b.y);
        o[6] = (short)f2bf(b.z); o[7] = (short)f2bf(b.w);
    } else {
        for (int j = 0; j < 8; j++) o[j] = 0;
    }
    *(s16x8*)(x_pad + off) = o;
}

__global__ void fill_s(const float* __restrict__ s_x, const float* __restrict__ pos,
                       uint16_t* __restrict__ s_pad) {
    int chunk = blockIdx.x * 256 + threadIdx.x;
    const int total = M_PAD * (DIM / 8);
    if (chunk >= total) return;
    int i = chunk / (DIM / 8);
    int cc = chunk - i * (DIM / 8);
    int d0 = cc * 8;
    uint16_t* dst = s_pad + (size_t)i * DIM + d0;
    if (i >= M_REAL) {
        s16x8 z; for (int j = 0; j < 8; j++) z[j] = 0;
        *(s16x8*)dst = z;
        return;
    }
    int b = i / NK, rr = i - b * NK;
    int t_i = rr / NSPACE, n_i = rr - t_i * NSPACE;
    const float* src = s_x + ((size_t)(n_i * (BATCH * TFRAMES) + b * TFRAMES + t_i)) * DIM + d0;
    const float* ps = pos + (size_t)rr * DIM + d0;
    float4 a0 = *(const float4*)src;
    float4 a1 = *(const float4*)(src + 4);
    float4 p0 = *(const float4*)ps;
    float4 p1 = *(const float4*)(ps + 4);
    s16x8 o;
    o[0] = (short)f2bf(a0.x + p0.x); o[1] = (short)f2bf(a0.y + p0.y);
    o[2] = (short)f2bf(a0.z + p0.z); o[3] = (short)f2bf(a0.w + p0.w);
    o[4] = (short)f2bf(a1.x + p1.x); o[5] = (short)f2bf(a1.y + p1.y);
    o[6] = (short)f2bf(a1.z + p1.z); o[7] = (short)f2bf(a1.w + p1.w);
    *(s16x8*)dst = o;
}

// ---------------- GEMM: C[M,N] = A[M,K=768] @ W[N,K=768]^T + bias ----------------
// MODE 0: Q    -> out0 = q_buf (B,H,NQ,64) bf16, scaled by 0.125*log2(e)
// MODE 1: KV   -> out0 = k_buf; out1 = v_buf (both (B,H,NK,64) bf16 row-major)
// MODE 2: proj -> outf = row-major (M_REAL, 768) fp32 output
template <int MODE>
__global__ __launch_bounds__(256)
void gemm_bt(const uint16_t* __restrict__ A, const uint16_t* __restrict__ W,
             const float* __restrict__ bias,
             uint16_t* __restrict__ out0, uint16_t* __restrict__ out1,
             float* __restrict__ outf) {
    __shared__ uint16_t As[128 * 40];
    __shared__ uint16_t Bs[128 * 40];
    const int t = threadIdx.x;
    const int lane = t & 63, w = t >> 6;
    const int r16 = lane & 15, quad = lane >> 4;
    const int wm = w >> 1, wn = w & 1;
    const int m0 = blockIdx.y * 128;
    const int n0 = blockIdx.x * 128;

    f32x4 acc[4][4];
    for (int a = 0; a < 4; a++)
        for (int bb = 0; bb < 4; bb++)
            for (int r = 0; r < 4; r++) acc[a][bb][r] = 0.f;

    for (int kk = 0; kk < DIM; kk += 32) {
        for (int i2 = 0; i2 < 2; i2++) {
            int c = t + i2 * 256;
            int row = c >> 2, kc = (c & 3) * 8;
            *(s16x8*)&As[row * 40 + kc] = *(const s16x8*)&A[(size_t)(m0 + row) * DIM + kk + kc];
            *(s16x8*)&Bs[row * 40 + kc] = *(const s16x8*)&W[(size_t)(n0 + row) * DIM + kk + kc];
        }
        __syncthreads();
        s16x8 af[4], bfr[4];
        for (int mt = 0; mt < 4; mt++)
            af[mt] = *(const s16x8*)&As[(wm * 64 + mt * 16 + r16) * 40 + quad * 8];
        for (int nt = 0; nt < 4; nt++)
            bfr[nt] = *(const s16x8*)&Bs[(wn * 64 + nt * 16 + r16) * 40 + quad * 8];
        for (int mt = 0; mt < 4; mt++)
            for (int nt = 0; nt < 4; nt++)
                acc[mt][nt] = __builtin_amdgcn_mfma_f32_16x16x32_bf16(af[mt], bfr[nt], acc[mt][nt], 0, 0, 0);
        __syncthreads();
    }

    for (int mt = 0; mt < 4; mt++)
        for (int nt = 0; nt < 4; nt++) {
            int col = n0 + wn * 64 + nt * 16 + r16;
            float bz = bias[col];
            int rowb = m0 + wm * 64 + mt * 16 + quad * 4;
            for (int r = 0; r < 4; r++) {
                int i = rowb + r;
                if (i >= M_REAL) continue;
                float v = acc[mt][nt][r] + bz;
                if (MODE == 0) {
                    int b = i / NQ, nq = i - b * NQ;
                    int h = col >> 6, d = col & 63;
                    out0[(size_t)(((b * NH + h) * NQ) + nq) * HD + d] = f2bf(v * 0.18033688011112042f);
                } else if (MODE == 1) {
                    int b = i / NK, nk = i - b * NK;
                    if (col < DIM) {
                        int h = col >> 6, d = col & 63;
                        out0[(size_t)(((b * NH + h) * NK) + nk) * HD + d] = f2bf(v);
                    } else {
                        int c2 = col - DIM;
                        int h = c2 >> 6, d = c2 & 63;
                        out1[(size_t)(((b * NH + h) * NK) + nk) * HD + d] = f2bf(v);
                    }
                } else {
                    outf[(size_t)i * DIM + col] = v;
                }
            }
        }
}

// ---------------- V transpose: (b,h,nk,64) -> (b,h,64,VT_LD) ----------------
__global__ __launch_bounds__(256)
void transpose_v(const uint16_t* __restrict__ v, uint16_t* __restrict__ vt) {
    __shared__ uint16_t T[64 * 72];
    int tile = blockIdx.x, bh = blockIdx.y;
    int nk0 = tile * 64;
    const uint16_t* V = v + (size_t)bh * NK * HD;
    uint16_t* VT = vt + (size_t)bh * HD * VT_LD;
    int tid = threadIdx.x;
    int rr = tid >> 3;
    int c8 = (tid & 7) * 8;
    for (int p = 0; p < 2; p++) {
        int lr = p * 32 + rr;
        int nk = nk0 + lr;
        s16x8 val;
        if (nk < NK) val = *(const s16x8*)(V + (size_t)nk * HD + c8);
        else for (int j = 0; j < 8; j++) val[j] = 0;
        for (int j = 0; j < 8; j++)
            T[(c8 + j) * 72 + lr] = (uint16_t)val[j];
    }
    __syncthreads();
    for (int p = 0; p < 2; p++) {
        int d = p * 32 + rr;
        s16x8 o = *(const s16x8*)&T[d * 72 + c8];
        *(s16x8*)(VT + (size_t)d * VT_LD + nk0 + c8) = o;
    }
}

// ---------------- flash attention v4: wg-shared LDS K/VT staging ----------------
// 256 threads = 4 waves x 32 q-rows (128 q/wg). Per 32-key iter, the wg stages
// K (4 KB contiguous) + VT (4 KB) once into double-buffered LDS; waves read
// fragments via ds_read_b128. K stored slot-PERMUTED (slot s <-> row rowA(s))
// so the lane->key mapping is identical to verified v3 register path.
// Row strides: K' 72 shorts, VT' 40 shorts -> fragment reads 2-way (free).
#define NITER 50
__global__ __launch_bounds__(256)
void flash_attn(const uint16_t* __restrict__ q_buf, const uint16_t* __restrict__ k_buf,
                const uint16_t* __restrict__ vt_buf, uint16_t* __restrict__ ao) {
    __shared__ uint16_t Kb[2][32 * 72];
    __shared__ uint16_t Vb[2][64 * 40];
    int h = blockIdx.y, b = blockIdx.z;
    int tid = threadIdx.x;
    int lane = tid & 63, w = tid >> 6;
    int r16 = lane & 15, quad = lane >> 4;
    size_t bh = (size_t)(b * NH + h);
    const uint16_t* Q = q_buf + bh * NQ * HD;
    const uint16_t* K = k_buf + bh * NK * HD;
    const uint16_t* VT = vt_buf + bh * HD * VT_LD;
    int q0 = blockIdx.x * 128 + w * 32;

    // staging thread mapping (per 32-key tile)
    const int kg = tid >> 3;                 // K: local row 0..31
    const int kc = (tid & 7) * 8;            // K: col chunk (shorts)
    const int kslot = ((kg >> 3) << 2) + (kg & 3) + ((kg & 4) ? 16 : 0);  // perm slot
    const int vd = tid >> 2;                 // VT: d-row 0..63
    const int vc = (tid & 3) * 8;            // VT: key chunk (shorts)
    const uint16_t* Kg = K + (size_t)kg * HD + kc;      // + kb*HD
    const uint16_t* Vg = VT + (size_t)vd * VT_LD + vc;  // + kb
    uint16_t* Kw = &Kb[0][kslot * 72 + kc];
    uint16_t* Vw = &Vb[0][vd * 40 + vc];
    const int KBSZ = 32 * 72, VBSZ = 64 * 40;

    s16x8 qf[2][2];
    for (int m = 0; m < 2; m++) {
        int qrow = q0 + m * 16 + r16;
        if (qrow < NQ) {
            qf[m][0] = *(const s16x8*)(Q + (size_t)qrow * HD + quad * 8);
            qf[m][1] = *(const s16x8*)(Q + (size_t)qrow * HD + 32 + quad * 8);
        } else {
            for (int j = 0; j < 8; j++) { qf[m][0][j] = 0; qf[m][1][j] = 0; }
        }
    }

    f32x4 oT[2][4];
    f32x4 lsum4[2];
    for (int m = 0; m < 2; m++) {
        for (int dt = 0; dt < 4; dt++)
            for (int r = 0; r < 4; r++) oT[m][dt][r] = 0.f;
        for (int r = 0; r < 4; r++) lsum4[m][r] = 0.f;
    }

    // prologue: stage tile 0 into buffer 0
    {
        s16x8 kv = *(const s16x8*)Kg;
        s16x8 vv = *(const s16x8*)Vg;
        *(s16x8*)Kw = kv;
        *(s16x8*)Vw = vv;
    }
    __syncthreads();

    for (int it = 0; it < NITER; it++) {
        int kb = it * 32;
        int cur = it & 1, nxt = cur ^ 1;
        // issue next tile's global loads early (land during compute)
        s16x8 knv, vnv;
        bool have_next = (it + 1 < NITER);
        if (have_next) {
            knv = *(const s16x8*)(Kg + (size_t)(kb + 32) * HD);
            vnv = *(const s16x8*)(Vg + kb + 32);
        }

        // fragments from LDS (current buffer)
        const uint16_t* Kc = &Kb[cur][0];
        const uint16_t* Vc = &Vb[cur][0];
        s16x8 kfA0 = *(const s16x8*)(Kc + r16 * 72 + quad * 8);
        s16x8 kfA1 = *(const s16x8*)(Kc + r16 * 72 + 32 + quad * 8);
        s16x8 kfB0 = *(const s16x8*)(Kc + (16 + r16) * 72 + quad * 8);
        s16x8 kfB1 = *(const s16x8*)(Kc + (16 + r16) * 72 + 32 + quad * 8);

        s16x8 pf[2];
        if (it < NITER - 1) {
            #pragma unroll
            for (int m = 0; m < 2; m++) {
                f32x4 sA, sB;
                for (int r = 0; r < 4; r++) { sA[r] = 0.f; sB[r] = 0.f; }
                sA = __builtin_amdgcn_mfma_f32_16x16x32_bf16(kfA0, qf[m][0], sA, 0, 0, 0);
                sA = __builtin_amdgcn_mfma_f32_16x16x32_bf16(kfA1, qf[m][1], sA, 0, 0, 0);
                sB = __builtin_amdgcn_mfma_f32_16x16x32_bf16(kfB0, qf[m][0], sB, 0, 0, 0);
                sB = __builtin_amdgcn_mfma_f32_16x16x32_bf16(kfB1, qf[m][1], sB, 0, 0, 0);
                f32x4 pA, pB;
                #pragma unroll
                for (int r = 0; r < 4; r++) { pA[r] = exp2f(sA[r]); pB[r] = exp2f(sB[r]); }
                lsum4[m] += pA;
                lsum4[m] += pB;
                union { s16x8 v; uint32_t u[4]; } pk;
                pk.u[0] = pack2bf(pA[0], pA[1]);
                pk.u[1] = pack2bf(pA[2], pA[3]);
                pk.u[2] = pack2bf(pB[0], pB[1]);
                pk.u[3] = pack2bf(pB[2], pB[3]);
                pf[m] = pk.v;
            }
        } else {  // tail: keys kb+8.. invalid
            #pragma unroll
            for (int m = 0; m < 2; m++) {
                f32x4 sA, sB;
                for (int r = 0; r < 4; r++) { sA[r] = 0.f; sB[r] = 0.f; }
                sA = __builtin_amdgcn_mfma_f32_16x16x32_bf16(kfA0, qf[m][0], sA, 0, 0, 0);
                sA = __builtin_amdgcn_mfma_f32_16x16x32_bf16(kfA1, qf[m][1], sA, 0, 0, 0);
                sB = __builtin_amdgcn_mfma_f32_16x16x32_bf16(kfB0, qf[m][0], sB, 0, 0, 0);
                sB = __builtin_amdgcn_mfma_f32_16x16x32_bf16(kfB1, qf[m][1], sB, 0, 0, 0);
                f32x4 pA, pB;
                #pragma unroll
                for (int r = 0; r < 4; r++) {
                    pA[r] = (kb + quad * 8 + r < NK)     ? exp2f(sA[r]) : 0.f;
                    pB[r] = (kb + quad * 8 + 4 + r < NK) ? exp2f(sB[r]) : 0.f;
                }
                lsum4[m] += pA;
                lsum4[m] += pB;
                union { s16x8 v; uint32_t u[4]; } pk;
                pk.u[0] = pack2bf(pA[0], pA[1]);
                pk.u[1] = pack2bf(pA[2], pA[3]);
                pk.u[2] = pack2bf(pB[0], pB[1]);
                pk.u[3] = pack2bf(pB[2], pB[3]);
                pf[m] = pk.v;
            }
        }
        #pragma unroll
        for (int dt = 0; dt < 4; dt++) {
            s16x8 vf = *(const s16x8*)(Vc + (dt * 16 + r16) * 40 + quad * 8);
            oT[0][dt] = __builtin_amdgcn_mfma_f32_16x16x32_bf16(vf, pf[0], oT[0][dt], 0, 0, 0);
            oT[1][dt] = __builtin_amdgcn_mfma_f32_16x16x32_bf16(vf, pf[1], oT[1][dt], 0, 0, 0);
        }
        if (have_next) {
            *(s16x8*)(Kw + nxt * KBSZ) = knv;
            *(s16x8*)(Vw + nxt * VBSZ) = vnv;
        }
        __syncthreads();
    }

    #pragma unroll
    for (int m = 0; m < 2; m++) {
        float rs = lsum4[m][0] + lsum4[m][1] + lsum4[m][2] + lsum4[m][3];
        rs += __shfl_xor(rs, 16);
        rs += __shfl_xor(rs, 32);
        int q = q0 + m * 16 + r16;
        if (q >= NQ) continue;
        float inv = 1.0f / rs;
        size_t rowoff = (size_t)(b * NQ + q) * DIM + h * HD;
        #pragma unroll
        for (int dt = 0; dt < 4; dt++) {
            s16x4 o4;
            o4[0] = (short)f2bf(oT[m][dt][0] * inv);
            o4[1] = (short)f2bf(oT[m][dt][1] * inv);
            o4[2] = (short)f2bf(oT[m][dt][2] * inv);
            o4[3] = (short)f2bf(oT[m][dt][3] * inv);
            *(s16x4*)(ao + rowoff + dt * 16 + quad * 4) = o4;
        }
    }
}

// ---------------- launch ----------------
extern "C" void kernel_launch(void* const* d_in, const int* in_sizes, int n_in,
                              void* d_out, int out_size, void* d_ws, size_t ws_size,
                              hipStream_t stream) {
    const float* s_x    = (const float*)d_in[0];
    const float* t_x    = (const float*)d_in[1];
    const float* pos    = (const float*)d_in[2];
    const float* q_w    = (const float*)d_in[3];
    const float* q_b    = (const float*)d_in[4];
    const float* kv_w   = (const float*)d_in[5];
    const float* kv_b   = (const float*)d_in[6];
    const float* proj_w = (const float*)d_in[7];
    const float* proj_b = (const float*)d_in[8];
    float* out = (float*)d_out;

    char* ws = (char*)d_ws;
    size_t off = 0;
    auto carve = [&](size_t bytes) {
        void* p = ws + off;
        off += (bytes + 255) & ~(size_t)255;
        return p;
    };
    uint16_t* x_pad  = (uint16_t*)carve((size_t)M_PAD * DIM * 2);
    uint16_t* s_pad  = (uint16_t*)carve((size_t)M_PAD * DIM * 2);
    uint16_t* q_buf  = (uint16_t*)carve((size_t)BATCH * NH * NQ * HD * 2);
    uint16_t* k_buf  = (uint16_t*)carve((size_t)BATCH * NH * NK * HD * 2);
    uint16_t* vt_buf = (uint16_t*)carve((size_t)BATCH * NH * HD * VT_LD * 2);
    uint16_t* wbuf   = (uint16_t*)carve((size_t)2 * DIM * DIM * 2);
    if (off > ws_size) return;
    uint16_t* v_buf = x_pad;   // x_pad dead after Q GEMM
    uint16_t* ao    = x_pad;   // v_buf dead after transpose

    const int fill_blocks = (M_PAD * (DIM / 8) + 255) / 256;
    const int wq8 = DIM * DIM / 8, wkv8 = 2 * DIM * DIM / 8;

    fill_x<<<fill_blocks, 256, 0, stream>>>(t_x, x_pad);
    fill_s<<<fill_blocks, 256, 0, stream>>>(s_x, pos, s_pad);

    conv_f2b<<<(wq8 + 255) / 256, 256, 0, stream>>>(q_w, wbuf, wq8);
    gemm_bt<0><<<dim3(DIM / 128, M_PAD / 128), 256, 0, stream>>>(x_pad, wbuf, q_b, q_buf, nullptr, nullptr);

    conv_f2b<<<(wkv8 + 255) / 256, 256, 0, stream>>>(kv_w, wbuf, wkv8);
    gemm_bt<1><<<dim3(2 * DIM / 128, M_PAD / 128), 256, 0, stream>>>(s_pad, wbuf, kv_b, k_buf, v_buf, nullptr);
    transpose_v<<<dim3(VT_LD / 64, BATCH * NH), 256, 0, stream>>>(v_buf, vt_buf);

    flash_attn<<<dim3((NQ + 127) / 128, NH, BATCH), 256, 0, stream>>>(q_buf, k_buf, vt_buf, ao);

    conv_f2b<<<(wq8 + 255) / 256, 256, 0, stream>>>(proj_w, wbuf, wq8);
    gemm_bt<2><<<dim3(DIM / 128, M_PAD / 128), 256, 0, stream>>>(ao, wbuf, proj_b, nullptr, nullptr, out);
}